// Round 1
// 816.159 us; speedup vs baseline: 1.0535x; 1.0535x over previous
//
#include <hip/hip_runtime.h>

#define N_VOX 200000
#define NPAD_INV (27 * N_VOX + 128)
#define EPS_BN 1e-5f

typedef __bf16 bf16x8 __attribute__((ext_vector_type(8)));
typedef float f32x4 __attribute__((ext_vector_type(4)));

__device__ __forceinline__ float bf2f(unsigned short u) {
    union { float f; unsigned int i; } x; x.i = ((unsigned int)u) << 16; return x.f;
}
__device__ __forceinline__ unsigned short f2bf(float f) {
    union { float f; unsigned int i; } x; x.f = f;
    unsigned int r = x.i + 0x7fffu + ((x.i >> 16) & 1u);  // RNE
    return (unsigned short)(r >> 16);
}

// async 16B/lane global->LDS; LDS dest = wave-uniform base + lane*16
#define ASYNC16(gsrc, ldst)                                                             \
    __builtin_amdgcn_global_load_lds(                                                   \
        (const __attribute__((address_space(1))) void*)(gsrc),                          \
        (__attribute__((address_space(3))) void*)(ldst), 16, 0, 0)

// ---------------- inverse kernel-map ----------------
__global__ void fill_inv_kernel(int* __restrict__ inv) {
    for (int i = blockIdx.x * 256 + threadIdx.x; i < NPAD_INV; i += gridDim.x * 256)
        inv[i] = N_VOX;
}

__global__ void build_inv_kernel(const int* __restrict__ sidx, const int* __restrict__ gidx,
                                 int* __restrict__ inv) {
    int k = blockIdx.y;
    int p = blockIdx.x * 256 + threadIdx.x;
    if (p < N_VOX) {
        int s = sidx[k * N_VOX + p];
        if (s < N_VOX) inv[k * N_VOX + s] = gidx[k * N_VOX + p];  // unique s per k -> no race
    }
}

// ---------------- weight transpose + fp32->bf16: w[k][a][b] -> wt[k][b][a] ----------------
__global__ void tr_w1_kernel(const float* __restrict__ w, unsigned short* __restrict__ wt) {
    int k = blockIdx.y; int idx = blockIdx.x * 256 + threadIdx.x;  // < 8192
    int a = idx >> 7, b = idx & 127;
    wt[k * 8192 + b * 64 + a] = f2bf(w[k * 8192 + idx]);
}
__global__ void tr_w2_kernel(const float* __restrict__ w, unsigned short* __restrict__ wt) {
    int k = blockIdx.y; int idx = blockIdx.x * 256 + threadIdx.x;  // < 16384
    int a = idx >> 7, b = idx & 127;
    wt[k * 16384 + b * 128 + a] = f2bf(w[k * 16384 + idx]);
}
__global__ void tr_wn_kernel(const float* __restrict__ w, unsigned short* __restrict__ wt) {
    int idx = blockIdx.x * 256 + threadIdx.x;  // < 8192
    int a = idx >> 7, b = idx & 127;
    wt[b * 64 + a] = f2bf(w[idx]);
}

// ---------------- BN stats ----------------
__global__ void stats1_kernel(const float* __restrict__ feats,
                              float* __restrict__ sum, float* __restrict__ sq) {
    int t = threadIdx.x; int c = t & 63; int rg = t >> 6;
    float s = 0.f, q = 0.f;
    for (int row = blockIdx.x * 4 + rg; row < N_VOX; row += gridDim.x * 4) {
        float x = feats[(size_t)row * 64 + c];
        s += x; q += x * x;
    }
    __shared__ float red[8][64];
    red[rg][c] = s; red[4 + rg][c] = q;
    __syncthreads();
    if (t < 64) atomicAdd(&sum[t], red[0][t] + red[1][t] + red[2][t] + red[3][t]);
    else if (t < 128) { int cc = t - 64; atomicAdd(&sq[cc], red[4][cc] + red[5][cc] + red[6][cc] + red[7][cc]); }
}

__global__ void stats2_kernel(const unsigned short* __restrict__ h1b,
                              float* __restrict__ sum, float* __restrict__ sq) {
    int t = threadIdx.x; int c = t & 127; int rg = t >> 7;
    float s = 0.f, q = 0.f;
    for (int row = blockIdx.x * 2 + rg; row < N_VOX; row += gridDim.x * 2) {
        float x = bf2f(h1b[(size_t)row * 128 + c]);
        s += x; q += x * x;
    }
    __shared__ float red[4][128];
    red[rg][c] = s; red[2 + rg][c] = q;
    __syncthreads();
    if (t < 128) atomicAdd(&sum[t], red[0][t] + red[1][t]);
    else { int cc = t - 128; atomicAdd(&sq[cc], red[2][cc] + red[3][cc]); }
}

// ---------------- norm1: fA = bf16(BN1(feats)), fRaw = bf16(feats) ----------------
__global__ void norm1_kernel(const float* __restrict__ feats, const float* __restrict__ ssum,
                             const float* __restrict__ ssq, const float* __restrict__ gamma,
                             const float* __restrict__ beta, unsigned short* __restrict__ fA,
                             unsigned short* __restrict__ fRaw) {
    __shared__ float sc[64], sh[64];
    int t = threadIdx.x;
    if (t < 64) {
        float mean = ssum[t] * (1.0f / N_VOX);
        float var  = ssq[t] * (1.0f / N_VOX) - mean * mean;
        float s    = gamma[t] * rsqrtf(var + EPS_BN);
        sc[t] = s; sh[t] = beta[t] - mean * s;
    }
    __syncthreads();
    const int total = N_VOX * 64 / 8;  // 8-elem chunks
    int i = blockIdx.x * 256 + t;
    if (i >= total) return;
    int cb = (i * 8) & 63;
    const float4* src = (const float4*)(feats + (size_t)i * 8);
    float4 f0 = src[0], f1 = src[1];
    float fv[8] = {f0.x, f0.y, f0.z, f0.w, f1.x, f1.y, f1.z, f1.w};
    union { uint4 q; unsigned short u[8]; } a, r;
#pragma unroll
    for (int j = 0; j < 8; j++) {
        a.u[j] = f2bf(fv[j] * sc[cb + j] + sh[cb + j]);
        r.u[j] = f2bf(fv[j]);
    }
    *(uint4*)(fA + (size_t)i * 8) = a.q;
    *(uint4*)(fRaw + (size_t)i * 8) = r.q;
}

// ---------------- norm2: h1b = bf16(BN2(h1b)) in-place ----------------
__global__ void norm2_kernel(unsigned short* __restrict__ h1b, const float* __restrict__ ssum,
                             const float* __restrict__ ssq, const float* __restrict__ gamma,
                             const float* __restrict__ beta) {
    __shared__ float sc[128], sh[128];
    int t = threadIdx.x;
    if (t < 128) {
        float mean = ssum[t] * (1.0f / N_VOX);
        float var  = ssq[t] * (1.0f / N_VOX) - mean * mean;
        float s    = gamma[t] * rsqrtf(var + EPS_BN);
        sc[t] = s; sh[t] = beta[t] - mean * s;
    }
    __syncthreads();
    const int total = N_VOX * 128 / 8;
    int i = blockIdx.x * 256 + t;
    if (i >= total) return;
    int cb = (i * 8) & 127;
    union { uint4 q; unsigned short u[8]; } v;
    v.q = *(const uint4*)(h1b + (size_t)i * 8);
#pragma unroll
    for (int j = 0; j < 8; j++) v.u[j] = f2bf(bf2f(v.u[j]) * sc[cb + j] + sh[cb + j]);
    *(uint4*)(h1b + (size_t)i * 8) = v.q;
}

// ---------------- conv1: h1[i] = sum_k fA[inv[k][i]] @ w1[k]  (64->128, bf16 out) ----------
// m97 structure: 128x128 tile, BK=64, 4 waves x (64x64 out, 4x4 acc), global_load_lds staging.
// LDS tiles are XOR-swizzled (T2, st-16B-chunk): LDS chunk c of row r holds global chunk
// c ^ (r&7). global_load_lds writes linearly, so the swizzle is applied by pre-swizzling the
// per-lane GLOBAL source column (rule #21), and un-applied on the ds_read address. This
// breaks the 16-way bank conflict of the 128 B-stride row-major tile (was 12 extra
// cycles per ds_read_b128, SQ_LDS_BANK_CONFLICT=6.6e7 on conv2).
__global__ __launch_bounds__(256) void conv1_kernel(
    const unsigned short* __restrict__ fA, const unsigned short* __restrict__ w1t,
    const int* __restrict__ inv, const unsigned short* __restrict__ zp,
    unsigned short* __restrict__ h1b) {
    __shared__ __align__(16) unsigned short sA[128 * 64];
    __shared__ __align__(16) unsigned short sB[128 * 64];
    const int t = threadIdx.x, lane = t & 63, w = t >> 6;
    const int v0 = blockIdx.x * 128;
    const int srow = w * 32;            // wave stages tile rows [srow, srow+32)
    const int lrow = lane >> 3;         // 8 lanes per row
    const int lcol = (lane & 7) * 8;    // linear LDS chunk this lane fills
    const int scol = lcol ^ (lrow * 8); // pre-swizzled global source column (rt&7 == lrow)
    const int m0 = (w & 1) * 64, n0 = (w >> 1) * 64;
    const int l16 = lane & 15, quad = lane >> 4;
    const int xs = l16 & 7;             // read-side swizzle key (row & 7)
    f32x4 acc[4][4] = {};

    for (int k = 0; k < 27; k++) {
#pragma unroll
        for (int q = 0; q < 4; q++) {
            int rt = srow + q * 8 + lrow;
            int g = inv[k * N_VOX + v0 + rt];
            const unsigned short* asrc = (g < N_VOX) ? (fA + (size_t)g * 64 + scol) : (zp + scol);
            ASYNC16(asrc, &sA[(srow + q * 8) * 64]);
            const unsigned short* bsrc = w1t + k * 8192 + rt * 64 + scol;
            ASYNC16(bsrc, &sB[(srow + q * 8) * 64]);
        }
        __syncthreads();
#pragma unroll
        for (int ks = 0; ks < 2; ks++) {
            const int cs = ((ks * 4 + quad) ^ xs) * 8;  // swizzled chunk for global col ks*32+quad*8
            bf16x8 af[4], bfr[4];
#pragma unroll
            for (int mi = 0; mi < 4; mi++)
                af[mi] = *(const bf16x8*)&sA[(m0 + mi * 16 + l16) * 64 + cs];
#pragma unroll
            for (int ni = 0; ni < 4; ni++)
                bfr[ni] = *(const bf16x8*)&sB[(n0 + ni * 16 + l16) * 64 + cs];
#pragma unroll
            for (int mi = 0; mi < 4; mi++)
#pragma unroll
                for (int ni = 0; ni < 4; ni++)
                    acc[mi][ni] = __builtin_amdgcn_mfma_f32_16x16x32_bf16(af[mi], bfr[ni], acc[mi][ni], 0, 0, 0);
        }
        __syncthreads();
    }
#pragma unroll
    for (int mi = 0; mi < 4; mi++)
#pragma unroll
        for (int r = 0; r < 4; r++) {
            int v = v0 + m0 + mi * 16 + quad * 4 + r;
            if (v < N_VOX) {
#pragma unroll
                for (int ni = 0; ni < 4; ni++)
                    h1b[(size_t)v * 128 + n0 + ni * 16 + l16] = f2bf(acc[mi][ni][r]);
            }
        }
}

// ------- conv2 + skip: out[i] = sum_k h1n[inv[k][i]] @ w2[k] + fRaw[i] @ w_nin (fp32 out) ----
// 55 BK=64 iters: jj<54 -> (ko=jj>>1, khalf=jj&1) of conv; jj==54 -> fused 1x1 skip.
// Same T2 XOR-swizzle as conv1.
__global__ __launch_bounds__(256) void conv2_kernel(
    const unsigned short* __restrict__ h1n, const unsigned short* __restrict__ fRaw,
    const unsigned short* __restrict__ w2t, const unsigned short* __restrict__ w_nint,
    const int* __restrict__ inv, const unsigned short* __restrict__ zp,
    float* __restrict__ out) {
    __shared__ __align__(16) unsigned short sA[128 * 64];
    __shared__ __align__(16) unsigned short sB[128 * 64];
    const int t = threadIdx.x, lane = t & 63, w = t >> 6;
    const int v0 = blockIdx.x * 128;
    const int srow = w * 32;
    const int lrow = lane >> 3;
    const int lcol = (lane & 7) * 8;
    const int scol = lcol ^ (lrow * 8);  // pre-swizzled global source column
    const int m0 = (w & 1) * 64, n0 = (w >> 1) * 64;
    const int l16 = lane & 15, quad = lane >> 4;
    const int xs = l16 & 7;
    f32x4 acc[4][4] = {};

    for (int jj = 0; jj < 55; jj++) {
        if (jj < 54) {
            const int ko = jj >> 1;
            const int kh = (jj & 1) * 64;
#pragma unroll
            for (int q = 0; q < 4; q++) {
                int rt = srow + q * 8 + lrow;
                int g = inv[ko * N_VOX + v0 + rt];
                const unsigned short* asrc = (g < N_VOX) ? (h1n + (size_t)g * 128 + kh + scol) : (zp + scol);
                ASYNC16(asrc, &sA[(srow + q * 8) * 64]);
                const unsigned short* bsrc = w2t + ko * 16384 + rt * 128 + kh + scol;
                ASYNC16(bsrc, &sB[(srow + q * 8) * 64]);
            }
        } else {
#pragma unroll
            for (int q = 0; q < 4; q++) {
                int rt = srow + q * 8 + lrow;
                int v = v0 + rt;
                const unsigned short* asrc = (v < N_VOX) ? (fRaw + (size_t)v * 64 + scol) : (zp + scol);
                ASYNC16(asrc, &sA[(srow + q * 8) * 64]);
                const unsigned short* bsrc = w_nint + rt * 64 + scol;
                ASYNC16(bsrc, &sB[(srow + q * 8) * 64]);
            }
        }
        __syncthreads();
#pragma unroll
        for (int ks = 0; ks < 2; ks++) {
            const int cs = ((ks * 4 + quad) ^ xs) * 8;
            bf16x8 af[4], bfr[4];
#pragma unroll
            for (int mi = 0; mi < 4; mi++)
                af[mi] = *(const bf16x8*)&sA[(m0 + mi * 16 + l16) * 64 + cs];
#pragma unroll
            for (int ni = 0; ni < 4; ni++)
                bfr[ni] = *(const bf16x8*)&sB[(n0 + ni * 16 + l16) * 64 + cs];
#pragma unroll
            for (int mi = 0; mi < 4; mi++)
#pragma unroll
                for (int ni = 0; ni < 4; ni++)
                    acc[mi][ni] = __builtin_amdgcn_mfma_f32_16x16x32_bf16(af[mi], bfr[ni], acc[mi][ni], 0, 0, 0);
        }
        __syncthreads();
    }
#pragma unroll
    for (int mi = 0; mi < 4; mi++)
#pragma unroll
        for (int r = 0; r < 4; r++) {
            int v = v0 + m0 + mi * 16 + quad * 4 + r;
            if (v < N_VOX) {
#pragma unroll
                for (int ni = 0; ni < 4; ni++)
                    out[(size_t)v * 128 + n0 + ni * 16 + l16] = acc[mi][ni][r];
            }
        }
}

extern "C" void kernel_launch(void* const* d_in, const int* in_sizes, int n_in,
                              void* d_out, int out_size, void* d_ws, size_t ws_size,
                              hipStream_t stream) {
    const float* feats = (const float*)d_in[0];
    const float* w1    = (const float*)d_in[1];
    const float* w2    = (const float*)d_in[2];
    const float* w_nin = (const float*)d_in[3];
    const float* g1    = (const float*)d_in[4];
    const float* b1    = (const float*)d_in[5];
    const float* g2    = (const float*)d_in[6];
    const float* b2    = (const float*)d_in[7];
    const int* gidx = (const int*)d_in[8];
    const int* sidx = (const int*)d_in[9];
    float* out = (float*)d_out;

    // workspace layout (total ~125.3 MB, all 16B-aligned)
    char* ws = (char*)d_ws;
    int* inv               = (int*)(ws);                          // 21,600,512
    unsigned short* fA     = (unsigned short*)(ws + 21600512);    // 25,600,000
    unsigned short* fRaw   = (unsigned short*)(ws + 47200512);    // 25,600,000
    unsigned short* h1b    = (unsigned short*)(ws + 72800512);    // 51,200,000
    unsigned short* w1t    = (unsigned short*)(ws + 124000512);   // 442,368
    unsigned short* w2t    = (unsigned short*)(ws + 124442880);   // 884,736
    unsigned short* w_nint = (unsigned short*)(ws + 125327616);   // 16,384
    float* stats           = (float*)(ws + 125344000);            // 1,536
    unsigned short* zp     = (unsigned short*)(ws + 125345536);   // 256 (zero page)
    float* s1sum = stats, *s1sq = stats + 64, *s2sum = stats + 128, *s2sq = stats + 256;

    hipMemsetAsync(stats, 0, 1536 + 256, stream);  // stats + zero page
    fill_inv_kernel<<<2048, 256, 0, stream>>>(inv);
    build_inv_kernel<<<dim3(782, 27), 256, 0, stream>>>(sidx, gidx, inv);
    tr_w1_kernel<<<dim3(32, 27), 256, 0, stream>>>(w1, w1t);
    tr_w2_kernel<<<dim3(64, 27), 256, 0, stream>>>(w2, w2t);
    tr_wn_kernel<<<32, 256, 0, stream>>>(w_nin, w_nint);
    stats1_kernel<<<512, 256, 0, stream>>>(feats, s1sum, s1sq);
    norm1_kernel<<<6250, 256, 0, stream>>>(feats, s1sum, s1sq, g1, b1, fA, fRaw);
    conv1_kernel<<<1563, 256, 0, stream>>>(fA, w1t, inv, zp, h1b);
    stats2_kernel<<<512, 256, 0, stream>>>(h1b, s2sum, s2sq);
    norm2_kernel<<<12500, 256, 0, stream>>>(h1b, s2sum, s2sq, g2, b2);
    conv2_kernel<<<1563, 256, 0, stream>>>(h1b, fRaw, w2t, w_nint, inv, zp, out);
}

// Round 2
// 757.055 us; speedup vs baseline: 1.1358x; 1.0781x over previous
//
#include <hip/hip_runtime.h>

#define N_VOX 200000
#define NPAD_INV (27 * N_VOX + 128)
#define EPS_BN 1e-5f

typedef __bf16 bf16x8 __attribute__((ext_vector_type(8)));
typedef float f32x4 __attribute__((ext_vector_type(4)));

__device__ __forceinline__ float bf2f(unsigned short u) {
    union { float f; unsigned int i; } x; x.i = ((unsigned int)u) << 16; return x.f;
}
__device__ __forceinline__ unsigned short f2bf(float f) {
    union { float f; unsigned int i; } x; x.f = f;
    unsigned int r = x.i + 0x7fffu + ((x.i >> 16) & 1u);  // RNE
    return (unsigned short)(r >> 16);
}

// async 16B/lane global->LDS; LDS dest = wave-uniform base + lane*16
#define ASYNC16(gsrc, ldst)                                                             \
    __builtin_amdgcn_global_load_lds(                                                   \
        (const __attribute__((address_space(1))) void*)(gsrc),                          \
        (__attribute__((address_space(3))) void*)(ldst), 16, 0, 0)

// ---------------- inverse kernel-map ----------------
__global__ void fill_inv_kernel(int* __restrict__ inv) {
    for (int i = blockIdx.x * 256 + threadIdx.x; i < NPAD_INV; i += gridDim.x * 256)
        inv[i] = N_VOX;
}

__global__ void build_inv_kernel(const int* __restrict__ sidx, const int* __restrict__ gidx,
                                 int* __restrict__ inv) {
    int k = blockIdx.y;
    int p = blockIdx.x * 256 + threadIdx.x;
    if (p < N_VOX) {
        int s = sidx[k * N_VOX + p];
        if (s < N_VOX) inv[k * N_VOX + s] = gidx[k * N_VOX + p];  // unique s per k -> no race
    }
}

// ---------------- weight transpose + fp32->bf16: w[k][a][b] -> wt[k][b][a] ----------------
__global__ void tr_w1_kernel(const float* __restrict__ w, unsigned short* __restrict__ wt) {
    int k = blockIdx.y; int idx = blockIdx.x * 256 + threadIdx.x;  // < 8192
    int a = idx >> 7, b = idx & 127;
    wt[k * 8192 + b * 64 + a] = f2bf(w[k * 8192 + idx]);
}
__global__ void tr_w2_kernel(const float* __restrict__ w, unsigned short* __restrict__ wt) {
    int k = blockIdx.y; int idx = blockIdx.x * 256 + threadIdx.x;  // < 16384
    int a = idx >> 7, b = idx & 127;
    wt[k * 16384 + b * 128 + a] = f2bf(w[k * 16384 + idx]);
}
__global__ void tr_wn_kernel(const float* __restrict__ w, unsigned short* __restrict__ wt) {
    int idx = blockIdx.x * 256 + threadIdx.x;  // < 8192
    int a = idx >> 7, b = idx & 127;
    wt[b * 64 + a] = f2bf(w[idx]);
}

// ---------------- BN stats ----------------
__global__ void stats1_kernel(const float* __restrict__ feats,
                              float* __restrict__ sum, float* __restrict__ sq) {
    int t = threadIdx.x; int c = t & 63; int rg = t >> 6;
    float s = 0.f, q = 0.f;
    for (int row = blockIdx.x * 4 + rg; row < N_VOX; row += gridDim.x * 4) {
        float x = feats[(size_t)row * 64 + c];
        s += x; q += x * x;
    }
    __shared__ float red[8][64];
    red[rg][c] = s; red[4 + rg][c] = q;
    __syncthreads();
    if (t < 64) atomicAdd(&sum[t], red[0][t] + red[1][t] + red[2][t] + red[3][t]);
    else if (t < 128) { int cc = t - 64; atomicAdd(&sq[cc], red[4][cc] + red[5][cc] + red[6][cc] + red[7][cc]); }
}

__global__ void stats2_kernel(const unsigned short* __restrict__ h1b,
                              float* __restrict__ sum, float* __restrict__ sq) {
    int t = threadIdx.x; int c = t & 127; int rg = t >> 7;
    float s = 0.f, q = 0.f;
    for (int row = blockIdx.x * 2 + rg; row < N_VOX; row += gridDim.x * 2) {
        float x = bf2f(h1b[(size_t)row * 128 + c]);
        s += x; q += x * x;
    }
    __shared__ float red[4][128];
    red[rg][c] = s; red[2 + rg][c] = q;
    __syncthreads();
    if (t < 128) atomicAdd(&sum[t], red[0][t] + red[1][t]);
    else { int cc = t - 128; atomicAdd(&sq[cc], red[2][cc] + red[3][cc]); }
}

// ---------------- norm1: fA = bf16(BN1(feats)), fRaw = bf16(feats) ----------------
__global__ void norm1_kernel(const float* __restrict__ feats, const float* __restrict__ ssum,
                             const float* __restrict__ ssq, const float* __restrict__ gamma,
                             const float* __restrict__ beta, unsigned short* __restrict__ fA,
                             unsigned short* __restrict__ fRaw) {
    __shared__ float sc[64], sh[64];
    int t = threadIdx.x;
    if (t < 64) {
        float mean = ssum[t] * (1.0f / N_VOX);
        float var  = ssq[t] * (1.0f / N_VOX) - mean * mean;
        float s    = gamma[t] * rsqrtf(var + EPS_BN);
        sc[t] = s; sh[t] = beta[t] - mean * s;
    }
    __syncthreads();
    const int total = N_VOX * 64 / 8;  // 8-elem chunks
    int i = blockIdx.x * 256 + t;
    if (i >= total) return;
    int cb = (i * 8) & 63;
    const float4* src = (const float4*)(feats + (size_t)i * 8);
    float4 f0 = src[0], f1 = src[1];
    float fv[8] = {f0.x, f0.y, f0.z, f0.w, f1.x, f1.y, f1.z, f1.w};
    union { uint4 q; unsigned short u[8]; } a, r;
#pragma unroll
    for (int j = 0; j < 8; j++) {
        a.u[j] = f2bf(fv[j] * sc[cb + j] + sh[cb + j]);
        r.u[j] = f2bf(fv[j]);
    }
    *(uint4*)(fA + (size_t)i * 8) = a.q;
    *(uint4*)(fRaw + (size_t)i * 8) = r.q;
}

// ---------------- norm2: h1b = bf16(BN2(h1b)) in-place ----------------
__global__ void norm2_kernel(unsigned short* __restrict__ h1b, const float* __restrict__ ssum,
                             const float* __restrict__ ssq, const float* __restrict__ gamma,
                             const float* __restrict__ beta) {
    __shared__ float sc[128], sh[128];
    int t = threadIdx.x;
    if (t < 128) {
        float mean = ssum[t] * (1.0f / N_VOX);
        float var  = ssq[t] * (1.0f / N_VOX) - mean * mean;
        float s    = gamma[t] * rsqrtf(var + EPS_BN);
        sc[t] = s; sh[t] = beta[t] - mean * s;
    }
    __syncthreads();
    const int total = N_VOX * 128 / 8;
    int i = blockIdx.x * 256 + t;
    if (i >= total) return;
    int cb = (i * 8) & 127;
    union { uint4 q; unsigned short u[8]; } v;
    v.q = *(const uint4*)(h1b + (size_t)i * 8);
#pragma unroll
    for (int j = 0; j < 8; j++) v.u[j] = f2bf(bf2f(v.u[j]) * sc[cb + j] + sh[cb + j]);
    *(uint4*)(h1b + (size_t)i * 8) = v.q;
}

// ---------------- conv1: h1[i] = sum_k fA[inv[k][i]] @ w1[k]  (64->128, bf16 out) ----------
// 128x128 tile, BK=64, 4 waves. T2 XOR-swizzled LDS (conflict-free, verified R1: 6.6e7 -> 0).
// R2: 2-deep software pipeline (T3/T4-lite). Double-buffered LDS; stage(j+1) issued at top
// of iter j; COUNTED s_waitcnt vmcnt(8) (never 0 mid-loop) + raw s_barrier. stage(j)'s
// gather latency is hidden under iter j-1's compute instead of a synchronous drain.
// Safety: after issuing stage(j+1)'s 8 ASYNC16s, vmcnt(8) leaves at most those 8 in
// flight -> all of stage(j) (older, in-order retirement) has completed before barrier#1.
// barrier#2 keeps stage(j+2) from overwriting buf[cb] while it is still being read.
__global__ __launch_bounds__(256) void conv1_kernel(
    const unsigned short* __restrict__ fA, const unsigned short* __restrict__ w1t,
    const int* __restrict__ inv, const unsigned short* __restrict__ zp,
    unsigned short* __restrict__ h1b) {
    __shared__ __align__(16) unsigned short sA[2][128 * 64];
    __shared__ __align__(16) unsigned short sB[2][128 * 64];
    const int t = threadIdx.x, lane = t & 63, w = t >> 6;
    const int v0 = blockIdx.x * 128;
    const int srow = w * 32;            // wave stages tile rows [srow, srow+32)
    const int lrow = lane >> 3;         // 8 lanes per row
    const int lcol = (lane & 7) * 8;    // linear LDS chunk this lane fills
    const int scol = lcol ^ (lrow * 8); // pre-swizzled global source column (rt&7 == lrow)
    const int m0 = (w & 1) * 64, n0 = (w >> 1) * 64;
    const int l16 = lane & 15, quad = lane >> 4;
    const int xs = l16 & 7;             // read-side swizzle key (row & 7)
    f32x4 acc[4][4] = {};

    auto stage = [&](int k, int b) {
#pragma unroll
        for (int q = 0; q < 4; q++) {
            int rt = srow + q * 8 + lrow;
            int g = inv[k * N_VOX + v0 + rt];
            const unsigned short* asrc = (g < N_VOX) ? (fA + (size_t)g * 64 + scol) : (zp + scol);
            ASYNC16(asrc, &sA[b][(srow + q * 8) * 64]);
            const unsigned short* bsrc = w1t + k * 8192 + rt * 64 + scol;
            ASYNC16(bsrc, &sB[b][(srow + q * 8) * 64]);
        }
    };

    stage(0, 0);
    for (int j = 0; j < 27; j++) {
        const int cb = j & 1;
        if (j + 1 < 27) {
            stage(j + 1, cb ^ 1);
            asm volatile("s_waitcnt vmcnt(8)" ::: "memory");  // stage(j) done; stage(j+1) in flight
        } else {
            asm volatile("s_waitcnt vmcnt(0)" ::: "memory");  // tail: drain stage(26)
        }
        __builtin_amdgcn_sched_barrier(0);
        __builtin_amdgcn_s_barrier();   // all waves' stage(j) writes visible
        __builtin_amdgcn_sched_barrier(0);
#pragma unroll
        for (int ks = 0; ks < 2; ks++) {
            const int cs = ((ks * 4 + quad) ^ xs) * 8;  // swizzled chunk for global col ks*32+quad*8
            bf16x8 af[4], bfr[4];
#pragma unroll
            for (int mi = 0; mi < 4; mi++)
                af[mi] = *(const bf16x8*)&sA[cb][(m0 + mi * 16 + l16) * 64 + cs];
#pragma unroll
            for (int ni = 0; ni < 4; ni++)
                bfr[ni] = *(const bf16x8*)&sB[cb][(n0 + ni * 16 + l16) * 64 + cs];
            __builtin_amdgcn_s_setprio(1);
#pragma unroll
            for (int mi = 0; mi < 4; mi++)
#pragma unroll
                for (int ni = 0; ni < 4; ni++)
                    acc[mi][ni] = __builtin_amdgcn_mfma_f32_16x16x32_bf16(af[mi], bfr[ni], acc[mi][ni], 0, 0, 0);
            __builtin_amdgcn_s_setprio(0);
        }
        __builtin_amdgcn_sched_barrier(0);
        __builtin_amdgcn_s_barrier();   // reads of buf[cb] done before stage(j+2) overwrites it
        __builtin_amdgcn_sched_barrier(0);
    }
#pragma unroll
    for (int mi = 0; mi < 4; mi++)
#pragma unroll
        for (int r = 0; r < 4; r++) {
            int v = v0 + m0 + mi * 16 + quad * 4 + r;
            if (v < N_VOX) {
#pragma unroll
                for (int ni = 0; ni < 4; ni++)
                    h1b[(size_t)v * 128 + n0 + ni * 16 + l16] = f2bf(acc[mi][ni][r]);
            }
        }
}

// ------- conv2 + skip: out[i] = sum_k h1n[inv[k][i]] @ w2[k] + fRaw[i] @ w_nin (fp32 out) ----
// 55 BK=64 iters: jj<54 -> (ko=jj>>1, khalf=jj&1) of conv; jj==54 -> fused 1x1 skip.
// Same T2 swizzle + R2 2-deep counted-vmcnt pipeline as conv1.
__global__ __launch_bounds__(256) void conv2_kernel(
    const unsigned short* __restrict__ h1n, const unsigned short* __restrict__ fRaw,
    const unsigned short* __restrict__ w2t, const unsigned short* __restrict__ w_nint,
    const int* __restrict__ inv, const unsigned short* __restrict__ zp,
    float* __restrict__ out) {
    __shared__ __align__(16) unsigned short sA[2][128 * 64];
    __shared__ __align__(16) unsigned short sB[2][128 * 64];
    const int t = threadIdx.x, lane = t & 63, w = t >> 6;
    const int v0 = blockIdx.x * 128;
    const int srow = w * 32;
    const int lrow = lane >> 3;
    const int lcol = (lane & 7) * 8;
    const int scol = lcol ^ (lrow * 8);  // pre-swizzled global source column
    const int m0 = (w & 1) * 64, n0 = (w >> 1) * 64;
    const int l16 = lane & 15, quad = lane >> 4;
    const int xs = l16 & 7;
    f32x4 acc[4][4] = {};

    auto stage = [&](int j, int b) {
        if (j < 54) {
            const int ko = j >> 1;
            const int kh = (j & 1) * 64;
#pragma unroll
            for (int q = 0; q < 4; q++) {
                int rt = srow + q * 8 + lrow;
                int g = inv[ko * N_VOX + v0 + rt];
                const unsigned short* asrc = (g < N_VOX) ? (h1n + (size_t)g * 128 + kh + scol) : (zp + scol);
                ASYNC16(asrc, &sA[b][(srow + q * 8) * 64]);
                const unsigned short* bsrc = w2t + ko * 16384 + rt * 128 + kh + scol;
                ASYNC16(bsrc, &sB[b][(srow + q * 8) * 64]);
            }
        } else {
#pragma unroll
            for (int q = 0; q < 4; q++) {
                int rt = srow + q * 8 + lrow;
                int v = v0 + rt;
                const unsigned short* asrc = (v < N_VOX) ? (fRaw + (size_t)v * 64 + scol) : (zp + scol);
                ASYNC16(asrc, &sA[b][(srow + q * 8) * 64]);
                const unsigned short* bsrc = w_nint + rt * 64 + scol;
                ASYNC16(bsrc, &sB[b][(srow + q * 8) * 64]);
            }
        }
    };

    stage(0, 0);
    for (int jj = 0; jj < 55; jj++) {
        const int cb = jj & 1;
        if (jj + 1 < 55) {
            stage(jj + 1, cb ^ 1);
            asm volatile("s_waitcnt vmcnt(8)" ::: "memory");  // stage(jj) done; stage(jj+1) in flight
        } else {
            asm volatile("s_waitcnt vmcnt(0)" ::: "memory");  // tail: drain stage(54)
        }
        __builtin_amdgcn_sched_barrier(0);
        __builtin_amdgcn_s_barrier();
        __builtin_amdgcn_sched_barrier(0);
#pragma unroll
        for (int ks = 0; ks < 2; ks++) {
            const int cs = ((ks * 4 + quad) ^ xs) * 8;
            bf16x8 af[4], bfr[4];
#pragma unroll
            for (int mi = 0; mi < 4; mi++)
                af[mi] = *(const bf16x8*)&sA[cb][(m0 + mi * 16 + l16) * 64 + cs];
#pragma unroll
            for (int ni = 0; ni < 4; ni++)
                bfr[ni] = *(const bf16x8*)&sB[cb][(n0 + ni * 16 + l16) * 64 + cs];
            __builtin_amdgcn_s_setprio(1);
#pragma unroll
            for (int mi = 0; mi < 4; mi++)
#pragma unroll
                for (int ni = 0; ni < 4; ni++)
                    acc[mi][ni] = __builtin_amdgcn_mfma_f32_16x16x32_bf16(af[mi], bfr[ni], acc[mi][ni], 0, 0, 0);
            __builtin_amdgcn_s_setprio(0);
        }
        __builtin_amdgcn_sched_barrier(0);
        __builtin_amdgcn_s_barrier();
        __builtin_amdgcn_sched_barrier(0);
    }
#pragma unroll
    for (int mi = 0; mi < 4; mi++)
#pragma unroll
        for (int r = 0; r < 4; r++) {
            int v = v0 + m0 + mi * 16 + quad * 4 + r;
            if (v < N_VOX) {
#pragma unroll
                for (int ni = 0; ni < 4; ni++)
                    out[(size_t)v * 128 + n0 + ni * 16 + l16] = acc[mi][ni][r];
            }
        }
}

extern "C" void kernel_launch(void* const* d_in, const int* in_sizes, int n_in,
                              void* d_out, int out_size, void* d_ws, size_t ws_size,
                              hipStream_t stream) {
    const float* feats = (const float*)d_in[0];
    const float* w1    = (const float*)d_in[1];
    const float* w2    = (const float*)d_in[2];
    const float* w_nin = (const float*)d_in[3];
    const float* g1    = (const float*)d_in[4];
    const float* b1    = (const float*)d_in[5];
    const float* g2    = (const float*)d_in[6];
    const float* b2    = (const float*)d_in[7];
    const int* gidx = (const int*)d_in[8];
    const int* sidx = (const int*)d_in[9];
    float* out = (float*)d_out;

    // workspace layout (total ~125.3 MB, all 16B-aligned)
    char* ws = (char*)d_ws;
    int* inv               = (int*)(ws);                          // 21,600,512
    unsigned short* fA     = (unsigned short*)(ws + 21600512);    // 25,600,000
    unsigned short* fRaw   = (unsigned short*)(ws + 47200512);    // 25,600,000
    unsigned short* h1b    = (unsigned short*)(ws + 72800512);    // 51,200,000
    unsigned short* w1t    = (unsigned short*)(ws + 124000512);   // 442,368
    unsigned short* w2t    = (unsigned short*)(ws + 124442880);   // 884,736
    unsigned short* w_nint = (unsigned short*)(ws + 125327616);   // 16,384
    float* stats           = (float*)(ws + 125344000);            // 1,536
    unsigned short* zp     = (unsigned short*)(ws + 125345536);   // 256 (zero page)
    float* s1sum = stats, *s1sq = stats + 64, *s2sum = stats + 128, *s2sq = stats + 256;

    hipMemsetAsync(stats, 0, 1536 + 256, stream);  // stats + zero page
    fill_inv_kernel<<<2048, 256, 0, stream>>>(inv);
    build_inv_kernel<<<dim3(782, 27), 256, 0, stream>>>(sidx, gidx, inv);
    tr_w1_kernel<<<dim3(32, 27), 256, 0, stream>>>(w1, w1t);
    tr_w2_kernel<<<dim3(64, 27), 256, 0, stream>>>(w2, w2t);
    tr_wn_kernel<<<32, 256, 0, stream>>>(w_nin, w_nint);
    stats1_kernel<<<512, 256, 0, stream>>>(feats, s1sum, s1sq);
    norm1_kernel<<<6250, 256, 0, stream>>>(feats, s1sum, s1sq, g1, b1, fA, fRaw);
    conv1_kernel<<<1563, 256, 0, stream>>>(fA, w1t, inv, zp, h1b);
    stats2_kernel<<<512, 256, 0, stream>>>(h1b, s2sum, s2sq);
    norm2_kernel<<<12500, 256, 0, stream>>>(h1b, s2sum, s2sq, g2, b2);
    conv2_kernel<<<1563, 256, 0, stream>>>(h1b, fRaw, w2t, w_nint, inv, zp, out);
}